// Round 11
// baseline (130.046 us; speedup 1.0000x reference)
//
#include <hip/hip_runtime.h>

#define NV    150000
#define CIN   32
#define COUT  64
#define EPSF  1e-5f
#define NCOPY 16

#define NTHR   256
#define NTILES (NV / 16)              // 9375 exact
// 2 tiles per wave: 4688 waves -> 1172 blocks
#define NBLK1  1172

// k_norm: chunks of 8 channels (one uint4 of bf16)
#define CH8    (NV * COUT / 8)        // 1,200,000
#define NBLK2  1172
#define STRIDE2 (NBLK2 * NTHR)        // 300,032 (divisible by 8)

// prep grid: feat blocks + 27 weight blocks + 1 gstats block
#define FEAT_T   (NV * CIN / 8)       // 600,000 threads, 8 floats each
#define FEATBLK  ((FEAT_T + NTHR - 1) / NTHR)   // 2344
#define PREPBLK  (FEATBLK + 27 + 1)             // 2372

// ws layout (bytes):
//   [0, 9600000)            ushort feat_bf[NV*CIN]
//   [9600000, 9710592)      ushort wfrag[27*4*64*8]  (B-fragment swizzled)
//   [9710592, 9718784)      float  gstats[NCOPY*128]
//   [9720832, 28920832)     ushort out_bf[NV*COUT]   (conv result, bf16)
#define WS_WFRAG  9600000
#define WS_GSTATS 9710592
#define WS_OUTBF  9720832

typedef short  bf16x8 __attribute__((ext_vector_type(8)));
typedef float  f32x4  __attribute__((ext_vector_type(4)));

union u4bf { uint4 u; bf16x8 h; };

__device__ __forceinline__ unsigned pack_bf2(float a, float b) {
    union { float f; unsigned u; } ca, cb;
    ca.f = a; cb.f = b;
    const unsigned lo = (ca.u + 0x7FFFu + ((ca.u >> 16) & 1u)) >> 16;
    const unsigned hi = (cb.u + 0x7FFFu + ((cb.u >> 16) & 1u)) & 0xFFFF0000u;
    return lo | hi;
}

__device__ __forceinline__ unsigned short bf16r(float a) {
    union { float f; unsigned u; } c; c.f = a;
    return (unsigned short)((c.u + 0x7FFFu + ((c.u >> 16) & 1u)) >> 16);
}

// ---------------------------------------------------------------------------
// K0: prep — feat->bf16, weights->B-fragment-swizzled bf16, zero gstats.
// ---------------------------------------------------------------------------
__global__ __launch_bounds__(NTHR) void k_prep(
    const float* __restrict__ feat,
    const float* __restrict__ weight,
    char*        __restrict__ ws)
{
    const int b = blockIdx.x;
    if (b < FEATBLK) {
        const int t = b * NTHR + threadIdx.x;
        if (t < FEAT_T) {
            const float4* src = (const float4*)(feat) + t * 2;
            const float4 f0 = src[0];
            const float4 f1 = src[1];
            uint4 o;
            o.x = pack_bf2(f0.x, f0.y);
            o.y = pack_bf2(f0.z, f0.w);
            o.z = pack_bf2(f1.x, f1.y);
            o.w = pack_bf2(f1.z, f1.w);
            ((uint4*)ws)[t] = o;
        }
    } else if (b < FEATBLK + 27) {
        const int k    = b - FEATBLK;
        const int bb   = threadIdx.x >> 6;       // cout block 0..3
        const int lane = threadIdx.x & 63;
        const int quad = lane >> 4;
        const int lm   = lane & 15;
        const float* wsrc = weight + (long)k * CIN * COUT + (quad * 8) * COUT + bb * 16 + lm;
        float f[8];
#pragma unroll
        for (int j = 0; j < 8; ++j) f[j] = wsrc[j * COUT];
        uint4 o;
        o.x = pack_bf2(f[0], f[1]);
        o.y = pack_bf2(f[2], f[3]);
        o.z = pack_bf2(f[4], f[5]);
        o.w = pack_bf2(f[6], f[7]);
        ((uint4*)(ws + WS_WFRAG))[(k * 4 + bb) * 64 + lane] = o;
    } else {
        float* gs = (float*)(ws + WS_GSTATS);
#pragma unroll
        for (int i = 0; i < 8; ++i) gs[threadIdx.x + i * NTHR] = 0.f;
    }
}

// ---------------------------------------------------------------------------
// K1: TWO tiles per wave, software-pipelined: both tiles' scan loads and
// center A-fragments issue before any processing, so tile 1's scan latency
// hides behind tile 0's ballots/drain/stores. All operands pre-converted
// bf16. Fused BN partials -> striped atomics.
// ---------------------------------------------------------------------------
__global__ __launch_bounds__(NTHR) void k_conv(
    char*        __restrict__ ws,      // feat_bf + wfrag + gstats + out_bf
    const int*   __restrict__ nbr,     // [27, NV]
    float*       __restrict__ gstats)
{
    const uint4* fb = (const uint4*)ws;                 // feat_bf rows: 4 uint4/row
    const uint4* wf = (const uint4*)(ws + WS_WFRAG);    // wfrag[(k*4+b)*64+lane]
    unsigned short* ob = (unsigned short*)(ws + WS_OUTBF);

    const int tid  = threadIdx.x;
    const int lane = tid & 63;
    const int quad = lane >> 4;
    const int lm   = lane & 15;
    const int wid  = blockIdx.x * 4 + (tid >> 6);   // wave id; tiles 2*wid, 2*wid+1

    f32x4 ssum = {0.f, 0.f, 0.f, 0.f};
    f32x4 qsum = {0.f, 0.f, 0.f, 0.f};

    const int t0 = wid * 2;
    const int t1 = wid * 2 + 1;
    const bool have0 = (t0 < NTILES);
    const bool have1 = (t1 < NTILES);
    const int v0a = have0 ? t0 * 16 : 0;
    const int v0b = have1 ? t1 * 16 : 0;

    // ---- 1) issue ALL scan loads (both tiles) ----
    int sidx[2][7];
#pragma unroll
    for (int it = 0; it < 7; ++it) {
        const int item = lane + it * 64;
        int idxA = -1, idxB = -1;
        if (item < 416) {
            const int kp = item >> 4;
            const int k  = kp + (kp >= 13);
            const long base = (long)k * NV + (item & 15);
            idxA = have0 ? nbr[base + v0a] : -1;
            idxB = have1 ? nbr[base + v0b] : -1;
        }
        sidx[0][it] = idxA;
        sidx[1][it] = idxB;
    }

    // ---- 2) issue both center A-fragments + shared center W ----
    u4bf a0, a1, wc[4];
    a0.u = fb[(v0a + lm) * 4 + quad];
    a1.u = fb[(v0b + lm) * 4 + quad];
#pragma unroll
    for (int b = 0; b < 4; ++b) wc[b].u = wf[(13 * 4 + b) * 64 + lane];

    // ---- 3) process each tile ----
#pragma unroll 1
    for (int t = 0; t < 2; ++t) {
        const bool have = t ? have1 : have0;
        if (!have) break;
        const int v0 = t ? v0b : v0a;

        f32x4 acc[4] = {{0.f,0.f,0.f,0.f},{0.f,0.f,0.f,0.f},{0.f,0.f,0.f,0.f},{0.f,0.f,0.f,0.f}};
        {
            const u4bf a = t ? a1 : a0;
#pragma unroll
            for (int b = 0; b < 4; ++b)
                acc[b] = __builtin_amdgcn_mfma_f32_16x16x32_bf16(a.h, wc[b].h, acc[b], 0, 0, 0);
        }

        // ballots -> wave-uniform 26-bit active-k mask
        unsigned int kmask = 0u;
#pragma unroll
        for (int it = 0; it < 7; ++it) {
            const unsigned long long m = __ballot(sidx[t][it] >= 0);
            kmask |= ((m & 0xFFFFull)         ? 1u : 0u) << (it * 4 + 0);
            kmask |= (((m >> 16) & 0xFFFFull) ? 1u : 0u) << (it * 4 + 1);
            kmask |= (((m >> 32) & 0xFFFFull) ? 1u : 0u) << (it * 4 + 2);
            kmask |= ((m >> 48)               ? 1u : 0u) << (it * 4 + 3);
        }

        // drain: 2 active k's per iteration
        while (kmask) {
            const int kpA = __ffs(kmask) - 1;
            kmask &= kmask - 1u;
            int kpB = -1;
            if (kmask) { kpB = __ffs(kmask) - 1; kmask &= kmask - 1u; }
            const int kA = kpA + (kpA >= 13);
            const int kB = (kpB >= 0) ? (kpB + (kpB >= 13)) : kA;

            int rawA, rawB;
            switch (kpA >> 2) {
                case 0: rawA = sidx[t][0]; break; case 1: rawA = sidx[t][1]; break;
                case 2: rawA = sidx[t][2]; break; case 3: rawA = sidx[t][3]; break;
                case 4: rawA = sidx[t][4]; break; case 5: rawA = sidx[t][5]; break;
                default: rawA = sidx[t][6]; break;
            }
            const int kpB2 = (kpB >= 0) ? kpB : kpA;
            switch (kpB2 >> 2) {
                case 0: rawB = sidx[t][0]; break; case 1: rawB = sidx[t][1]; break;
                case 2: rawB = sidx[t][2]; break; case 3: rawB = sidx[t][3]; break;
                case 4: rawB = sidx[t][4]; break; case 5: rawB = sidx[t][5]; break;
                default: rawB = sidx[t][6]; break;
            }
            const int idxA = __shfl(rawA, ((kpA & 3) << 4) | lm);
            int idxB = __shfl(rawB, ((kpB2 & 3) << 4) | lm);
            if (kpB < 0) idxB = -1;

            u4bf aA, aB;
            aA.u = fb[(long)(idxA < 0 ? 0 : idxA) * 4 + quad];
            aB.u = fb[(long)(idxB < 0 ? 0 : idxB) * 4 + quad];
            if (idxA < 0) aA.u = make_uint4(0u, 0u, 0u, 0u);
            if (idxB < 0) aB.u = make_uint4(0u, 0u, 0u, 0u);

#pragma unroll
            for (int b = 0; b < 4; ++b) {
                u4bf wA, wB;
                wA.u = wf[(kA * 4 + b) * 64 + lane];
                wB.u = wf[(kB * 4 + b) * 64 + lane];
                acc[b] = __builtin_amdgcn_mfma_f32_16x16x32_bf16(aA.h, wA.h, acc[b], 0, 0, 0);
                acc[b] = __builtin_amdgcn_mfma_f32_16x16x32_bf16(aB.h, wB.h, acc[b], 0, 0, 0);
            }
        }

        // store bf16 rows + BN partials from f32 values
#pragma unroll
        for (int b = 0; b < 4; ++b) {
            const float r0 = acc[b][0], r1 = acc[b][1], r2 = acc[b][2], r3 = acc[b][3];
            ob[(long)(v0 + quad * 4 + 0) * COUT + b * 16 + lm] = bf16r(r0);
            ob[(long)(v0 + quad * 4 + 1) * COUT + b * 16 + lm] = bf16r(r1);
            ob[(long)(v0 + quad * 4 + 2) * COUT + b * 16 + lm] = bf16r(r2);
            ob[(long)(v0 + quad * 4 + 3) * COUT + b * 16 + lm] = bf16r(r3);
            ssum[b] += r0 + r1 + r2 + r3;
            qsum[b] += r0 * r0 + r1 * r1 + r2 * r2 + r3 * r3;
        }
    }

    // ---- butterfly over quads ----
#pragma unroll
    for (int off = 16; off < 64; off <<= 1) {
#pragma unroll
        for (int b = 0; b < 4; ++b) {
            ssum[b] += __shfl_xor(ssum[b], off);
            qsum[b] += __shfl_xor(qsum[b], off);
        }
    }

    __shared__ float ls[4][128];
    const int wv = tid >> 6;
    if (quad == 0) {
#pragma unroll
        for (int b = 0; b < 4; ++b) {
            ls[wv][b * 16 + lm]      = ssum[b];
            ls[wv][64 + b * 16 + lm] = qsum[b];
        }
    }
    __syncthreads();
    if (tid < 128) {
        const float v = ls[0][tid] + ls[1][tid] + ls[2][tid] + ls[3][tid];
        atomicAdd(gstats + (blockIdx.x & (NCOPY - 1)) * 128 + tid, v);
    }
}

// ---------------------------------------------------------------------------
// K2: stripe reduce -> scale/shift, then read bf16 conv result, apply
// affine + ReLU, write f32 d_out.
// ---------------------------------------------------------------------------
__global__ __launch_bounds__(NTHR) void k_norm(
    const char*  __restrict__ ws_ro,   // out_bf
    float*       __restrict__ out,
    const float* __restrict__ gstats,
    const float* __restrict__ gamma,
    const float* __restrict__ beta)
{
    __shared__ float sscale[COUT];
    __shared__ float sshift[COUT];
    const int tid = threadIdx.x;
    if (tid < COUT) {
        float s = 0.f, q = 0.f;
#pragma unroll
        for (int cp = 0; cp < NCOPY; ++cp) {
            s += gstats[cp * 128 + tid];
            q += gstats[cp * 128 + 64 + tid];
        }
        const float inv_n = 1.f / (float)NV;
        const float mean = s * inv_n;
        float var = q * inv_n - mean * mean;
        var = fmaxf(var, 0.f);
        const float rstd = rsqrtf(var + EPSF);
        const float sc = gamma[tid] * rstd;
        sscale[tid] = sc;
        sshift[tid] = beta[tid] - mean * sc;
    }
    __syncthreads();

    const int  base = blockIdx.x * NTHR + tid;     // chunk id (8 channels)
    const int  g8   = (base & 7) * 8;              // fixed: STRIDE2 % 8 == 0
    const float4 SC0 = make_float4(sscale[g8],   sscale[g8+1], sscale[g8+2], sscale[g8+3]);
    const float4 SC1 = make_float4(sscale[g8+4], sscale[g8+5], sscale[g8+6], sscale[g8+7]);
    const float4 SH0 = make_float4(sshift[g8],   sshift[g8+1], sshift[g8+2], sshift[g8+3]);
    const float4 SH1 = make_float4(sshift[g8+4], sshift[g8+5], sshift[g8+6], sshift[g8+7]);

    const uint4* ib = (const uint4*)(ws_ro + WS_OUTBF);
    float4* o4 = (float4*)out;

#pragma unroll
    for (int n = 0; n < 4; ++n) {
        const int c = base + n * STRIDE2;
        if (n == 3 && c >= CH8) break;
        const uint4 u = ib[c];
        union { unsigned u; float f; } t;
        float4 v0, v1;
        t.u = u.x << 16;          v0.x = t.f;
        t.u = u.x & 0xFFFF0000u;  v0.y = t.f;
        t.u = u.y << 16;          v0.z = t.f;
        t.u = u.y & 0xFFFF0000u;  v0.w = t.f;
        t.u = u.z << 16;          v1.x = t.f;
        t.u = u.z & 0xFFFF0000u;  v1.y = t.f;
        t.u = u.w << 16;          v1.z = t.f;
        t.u = u.w & 0xFFFF0000u;  v1.w = t.f;

        v0.x = fmaxf(v0.x * SC0.x + SH0.x, 0.f);
        v0.y = fmaxf(v0.y * SC0.y + SH0.y, 0.f);
        v0.z = fmaxf(v0.z * SC0.z + SH0.z, 0.f);
        v0.w = fmaxf(v0.w * SC0.w + SH0.w, 0.f);
        v1.x = fmaxf(v1.x * SC1.x + SH1.x, 0.f);
        v1.y = fmaxf(v1.y * SC1.y + SH1.y, 0.f);
        v1.z = fmaxf(v1.z * SC1.z + SH1.z, 0.f);
        v1.w = fmaxf(v1.w * SC1.w + SH1.w, 0.f);

        o4[(long)c * 2]     = v0;
        o4[(long)c * 2 + 1] = v1;
    }
}

// ---------------------------------------------------------------------------
extern "C" void kernel_launch(void* const* d_in, const int* in_sizes, int n_in,
                              void* d_out, int out_size, void* d_ws, size_t ws_size,
                              hipStream_t stream) {
    const float* feat   = (const float*)d_in[0];
    const float* weight = (const float*)d_in[1];
    const float* gamma  = (const float*)d_in[2];
    const float* beta   = (const float*)d_in[3];
    const int*   nbr    = (const int*)d_in[4];
    float* out = (float*)d_out;

    char*  ws     = (char*)d_ws;
    float* gstats = (float*)(ws + WS_GSTATS);

    k_prep<<<PREPBLK, NTHR, 0, stream>>>(feat, weight, ws);
    k_conv<<<NBLK1, NTHR, 0, stream>>>(ws, nbr, gstats);
    k_norm<<<NBLK2, NTHR, 0, stream>>>(ws, out, gstats, gamma, beta);
}

// Round 12
// 118.883 us; speedup vs baseline: 1.0939x; 1.0939x over previous
//
#include <hip/hip_runtime.h>

#define NV    150000
#define CIN   32
#define COUT  64
#define EPSF  1e-5f
#define NCOPY 16

#define NTHR   256
#define NTILES (NV / 16)              // 9375 exact
#define NBLK1  ((NTILES + 3) / 4)     // 2344 blocks, 1 tile per wave

// k_norm: chunks of 8 channels (one uint4 of bf16)
#define CH8    (NV * COUT / 8)        // 1,200,000
#define NBLK2  1172
#define STRIDE2 (NBLK2 * NTHR)        // 300,032 (divisible by 8)

// prep grid: feat blocks + 27 weight blocks + 1 gstats block
#define FEAT_T   (NV * CIN / 8)       // 600,000 threads, 8 floats each
#define FEATBLK  ((FEAT_T + NTHR - 1) / NTHR)   // 2344
#define PREPBLK  (FEATBLK + 27 + 1)             // 2372

// ws layout (bytes):
//   [0, 9600000)            ushort feat_bf[NV*CIN]
//   [9600000, 9710592)      ushort wfrag[27*4*64*8]  (B-fragment swizzled)
//   [9710592, 9718784)      float  gstats[NCOPY*128]
//   [9720832, 28920832)     ushort out_bf[NV*COUT]   (conv result, bf16)
#define WS_WFRAG  9600000
#define WS_GSTATS 9710592
#define WS_OUTBF  9720832

typedef short  bf16x8 __attribute__((ext_vector_type(8)));
typedef float  f32x4  __attribute__((ext_vector_type(4)));

union u4bf { uint4 u; bf16x8 h; };

__device__ __forceinline__ unsigned pack_bf2(float a, float b) {
    union { float f; unsigned u; } ca, cb;
    ca.f = a; cb.f = b;
    const unsigned lo = (ca.u + 0x7FFFu + ((ca.u >> 16) & 1u)) >> 16;
    const unsigned hi = (cb.u + 0x7FFFu + ((cb.u >> 16) & 1u)) & 0xFFFF0000u;
    return lo | hi;
}

__device__ __forceinline__ unsigned short bf16r(float a) {
    union { float f; unsigned u; } c; c.f = a;
    return (unsigned short)((c.u + 0x7FFFu + ((c.u >> 16) & 1u)) >> 16);
}

// ---------------------------------------------------------------------------
// K0: prep — feat->bf16, weights->B-fragment-swizzled bf16, zero gstats.
// ---------------------------------------------------------------------------
__global__ __launch_bounds__(NTHR) void k_prep(
    const float* __restrict__ feat,
    const float* __restrict__ weight,
    char*        __restrict__ ws)
{
    const int b = blockIdx.x;
    if (b < FEATBLK) {
        const int t = b * NTHR + threadIdx.x;
        if (t < FEAT_T) {
            const float4* src = (const float4*)(feat) + t * 2;
            const float4 f0 = src[0];
            const float4 f1 = src[1];
            uint4 o;
            o.x = pack_bf2(f0.x, f0.y);
            o.y = pack_bf2(f0.z, f0.w);
            o.z = pack_bf2(f1.x, f1.y);
            o.w = pack_bf2(f1.z, f1.w);
            ((uint4*)ws)[t] = o;
        }
    } else if (b < FEATBLK + 27) {
        const int k    = b - FEATBLK;
        const int bb   = threadIdx.x >> 6;       // cout block 0..3
        const int lane = threadIdx.x & 63;
        const int quad = lane >> 4;
        const int lm   = lane & 15;
        const float* wsrc = weight + (long)k * CIN * COUT + (quad * 8) * COUT + bb * 16 + lm;
        float f[8];
#pragma unroll
        for (int j = 0; j < 8; ++j) f[j] = wsrc[j * COUT];
        uint4 o;
        o.x = pack_bf2(f[0], f[1]);
        o.y = pack_bf2(f[2], f[3]);
        o.z = pack_bf2(f[4], f[5]);
        o.w = pack_bf2(f[6], f[7]);
        ((uint4*)(ws + WS_WFRAG))[(k * 4 + bb) * 64 + lane] = o;
    } else {
        float* gs = (float*)(ws + WS_GSTATS);
#pragma unroll
        for (int i = 0; i < 8; ++i) gs[threadIdx.x + i * NTHR] = 0.f;
    }
}

// ---------------------------------------------------------------------------
// K1: one wave per 16-voxel tile. Center operand loads issue FIRST, then the
// 7 scan loads; center MFMA overlaps scan latency; drain processes each
// ballot group incrementally (group it only needs vmcnt(6-it)).
// ---------------------------------------------------------------------------
__global__ __launch_bounds__(NTHR) void k_conv(
    char*        __restrict__ ws,      // feat_bf + wfrag + gstats + out_bf
    const int*   __restrict__ nbr,     // [27, NV]
    float*       __restrict__ gstats)
{
    const uint4* fb = (const uint4*)ws;                 // feat_bf rows: 4 uint4/row
    const uint4* wf = (const uint4*)(ws + WS_WFRAG);    // wfrag[(k*4+b)*64+lane]
    unsigned short* ob = (unsigned short*)(ws + WS_OUTBF);

    const int tid  = threadIdx.x;
    const int lane = tid & 63;
    const int quad = lane >> 4;
    const int lm   = lane & 15;
    const int wid  = blockIdx.x * 4 + (tid >> 6);   // == tile id

    f32x4 ssum = {0.f, 0.f, 0.f, 0.f};
    f32x4 qsum = {0.f, 0.f, 0.f, 0.f};
    f32x4 acc[4] = {{0.f,0.f,0.f,0.f},{0.f,0.f,0.f,0.f},{0.f,0.f,0.f,0.f},{0.f,0.f,0.f,0.f}};

    const bool have_tile = (wid < NTILES);
    const int v0 = have_tile ? wid * 16 : 0;

    if (have_tile) {
        // ---- 1) center operand loads FIRST ----
        u4bf a0, wc[4];
        a0.u = fb[(v0 + lm) * 4 + quad];
#pragma unroll
        for (int b = 0; b < 4; ++b) wc[b].u = wf[(13 * 4 + b) * 64 + lane];

        // ---- 2) scan loads: 26 taps x 16 voxels = 416 items ----
        int sidx[7];
#pragma unroll
        for (int it = 0; it < 7; ++it) {
            const int item = lane + it * 64;
            int idx = -1;
            if (item < 416) {
                const int kp = item >> 4;
                const int k  = kp + (kp >= 13);
                idx = nbr[(long)k * NV + v0 + (item & 15)];
            }
            sidx[it] = idx;
        }

        // ---- 3) center MFMA (only needs the first 5 loads) ----
#pragma unroll
        for (int b = 0; b < 4; ++b)
            acc[b] = __builtin_amdgcn_mfma_f32_16x16x32_bf16(a0.h, wc[b].h, acc[b], 0, 0, 0);

        // ---- 4) incremental drain: per scan group (4 k's), ballot+drain ----
#pragma unroll 1
        for (int it = 0; it < 7; ++it) {
            const unsigned long long m = __ballot(sidx[it] >= 0);
            unsigned int gmask =
                ((m & 0xFFFFull)         ? 1u : 0u) |
                (((m >> 16) & 0xFFFFull) ? 2u : 0u) |
                (((m >> 32) & 0xFFFFull) ? 4u : 0u) |
                ((m >> 48)               ? 8u : 0u);

            while (gmask) {
                const int gA = __ffs(gmask) - 1;
                gmask &= gmask - 1u;
                int gB = -1;
                if (gmask) { gB = __ffs(gmask) - 1; gmask &= gmask - 1u; }

                const int kpA = it * 4 + gA;
                const int kpB2 = (gB >= 0) ? (it * 4 + gB) : kpA;
                const int kA = kpA + (kpA >= 13);
                const int kB = kpB2 + (kpB2 >= 13);

                const int idxA = __shfl(sidx[it], (gA << 4) | lm);
                int idxB = __shfl(sidx[it], ((kpB2 & 3) << 4) | lm);
                if (gB < 0) idxB = -1;

                u4bf aA, aB;
                aA.u = fb[(long)(idxA < 0 ? 0 : idxA) * 4 + quad];
                aB.u = fb[(long)(idxB < 0 ? 0 : idxB) * 4 + quad];
                if (idxA < 0) aA.u = make_uint4(0u, 0u, 0u, 0u);
                if (idxB < 0) aB.u = make_uint4(0u, 0u, 0u, 0u);

#pragma unroll
                for (int b = 0; b < 4; ++b) {
                    u4bf wA, wB;
                    wA.u = wf[(kA * 4 + b) * 64 + lane];
                    wB.u = wf[(kB * 4 + b) * 64 + lane];
                    acc[b] = __builtin_amdgcn_mfma_f32_16x16x32_bf16(aA.h, wA.h, acc[b], 0, 0, 0);
                    acc[b] = __builtin_amdgcn_mfma_f32_16x16x32_bf16(aB.h, wB.h, acc[b], 0, 0, 0);
                }
            }
        }

        // ---- 5) store bf16 rows + BN partials from f32 values ----
#pragma unroll
        for (int b = 0; b < 4; ++b) {
            const float r0 = acc[b][0], r1 = acc[b][1], r2 = acc[b][2], r3 = acc[b][3];
            ob[(long)(v0 + quad * 4 + 0) * COUT + b * 16 + lm] = bf16r(r0);
            ob[(long)(v0 + quad * 4 + 1) * COUT + b * 16 + lm] = bf16r(r1);
            ob[(long)(v0 + quad * 4 + 2) * COUT + b * 16 + lm] = bf16r(r2);
            ob[(long)(v0 + quad * 4 + 3) * COUT + b * 16 + lm] = bf16r(r3);
            ssum[b] += r0 + r1 + r2 + r3;
            qsum[b] += r0 * r0 + r1 * r1 + r2 * r2 + r3 * r3;
        }
    }

    // ---- butterfly over quads ----
#pragma unroll
    for (int off = 16; off < 64; off <<= 1) {
#pragma unroll
        for (int b = 0; b < 4; ++b) {
            ssum[b] += __shfl_xor(ssum[b], off);
            qsum[b] += __shfl_xor(qsum[b], off);
        }
    }

    __shared__ float ls[4][128];
    const int wv = tid >> 6;
    if (quad == 0) {
#pragma unroll
        for (int b = 0; b < 4; ++b) {
            ls[wv][b * 16 + lm]      = ssum[b];
            ls[wv][64 + b * 16 + lm] = qsum[b];
        }
    }
    __syncthreads();
    if (tid < 128) {
        const float v = ls[0][tid] + ls[1][tid] + ls[2][tid] + ls[3][tid];
        atomicAdd(gstats + (blockIdx.x & (NCOPY - 1)) * 128 + tid, v);
    }
}

// ---------------------------------------------------------------------------
// K2: stripe reduce -> scale/shift, then read bf16 conv result, apply
// affine + ReLU, write f32 d_out.
// ---------------------------------------------------------------------------
__global__ __launch_bounds__(NTHR) void k_norm(
    const char*  __restrict__ ws_ro,   // out_bf
    float*       __restrict__ out,
    const float* __restrict__ gstats,
    const float* __restrict__ gamma,
    const float* __restrict__ beta)
{
    __shared__ float sscale[COUT];
    __shared__ float sshift[COUT];
    const int tid = threadIdx.x;
    if (tid < COUT) {
        float s = 0.f, q = 0.f;
#pragma unroll
        for (int cp = 0; cp < NCOPY; ++cp) {
            s += gstats[cp * 128 + tid];
            q += gstats[cp * 128 + 64 + tid];
        }
        const float inv_n = 1.f / (float)NV;
        const float mean = s * inv_n;
        float var = q * inv_n - mean * mean;
        var = fmaxf(var, 0.f);
        const float rstd = rsqrtf(var + EPSF);
        const float sc = gamma[tid] * rstd;
        sscale[tid] = sc;
        sshift[tid] = beta[tid] - mean * sc;
    }
    __syncthreads();

    const int  base = blockIdx.x * NTHR + tid;     // chunk id (8 channels)
    const int  g8   = (base & 7) * 8;              // fixed: STRIDE2 % 8 == 0
    const float4 SC0 = make_float4(sscale[g8],   sscale[g8+1], sscale[g8+2], sscale[g8+3]);
    const float4 SC1 = make_float4(sscale[g8+4], sscale[g8+5], sscale[g8+6], sscale[g8+7]);
    const float4 SH0 = make_float4(sshift[g8],   sshift[g8+1], sshift[g8+2], sshift[g8+3]);
    const float4 SH1 = make_float4(sshift[g8+4], sshift[g8+5], sshift[g8+6], sshift[g8+7]);

    const uint4* ib = (const uint4*)(ws_ro + WS_OUTBF);
    float4* o4 = (float4*)out;

#pragma unroll
    for (int n = 0; n < 4; ++n) {
        const int c = base + n * STRIDE2;
        if (n == 3 && c >= CH8) break;
        const uint4 u = ib[c];
        union { unsigned u; float f; } t;
        float4 v0, v1;
        t.u = u.x << 16;          v0.x = t.f;
        t.u = u.x & 0xFFFF0000u;  v0.y = t.f;
        t.u = u.y << 16;          v0.z = t.f;
        t.u = u.y & 0xFFFF0000u;  v0.w = t.f;
        t.u = u.z << 16;          v1.x = t.f;
        t.u = u.z & 0xFFFF0000u;  v1.y = t.f;
        t.u = u.w << 16;          v1.z = t.f;
        t.u = u.w & 0xFFFF0000u;  v1.w = t.f;

        v0.x = fmaxf(v0.x * SC0.x + SH0.x, 0.f);
        v0.y = fmaxf(v0.y * SC0.y + SH0.y, 0.f);
        v0.z = fmaxf(v0.z * SC0.z + SH0.z, 0.f);
        v0.w = fmaxf(v0.w * SC0.w + SH0.w, 0.f);
        v1.x = fmaxf(v1.x * SC1.x + SH1.x, 0.f);
        v1.y = fmaxf(v1.y * SC1.y + SH1.y, 0.f);
        v1.z = fmaxf(v1.z * SC1.z + SH1.z, 0.f);
        v1.w = fmaxf(v1.w * SC1.w + SH1.w, 0.f);

        o4[(long)c * 2]     = v0;
        o4[(long)c * 2 + 1] = v1;
    }
}

// ---------------------------------------------------------------------------
extern "C" void kernel_launch(void* const* d_in, const int* in_sizes, int n_in,
                              void* d_out, int out_size, void* d_ws, size_t ws_size,
                              hipStream_t stream) {
    const float* feat   = (const float*)d_in[0];
    const float* weight = (const float*)d_in[1];
    const float* gamma  = (const float*)d_in[2];
    const float* beta   = (const float*)d_in[3];
    const int*   nbr    = (const int*)d_in[4];
    float* out = (float*)d_out;

    char*  ws     = (char*)d_ws;
    float* gstats = (float*)(ws + WS_GSTATS);

    k_prep<<<PREPBLK, NTHR, 0, stream>>>(feat, weight, ws);
    k_conv<<<NBLK1, NTHR, 0, stream>>>(ws, nbr, gstats);
    k_norm<<<NBLK2, NTHR, 0, stream>>>(ws, out, gstats, gamma, beta);
}

// Round 13
// 114.775 us; speedup vs baseline: 1.1330x; 1.0358x over previous
//
#include <hip/hip_runtime.h>

#define NV    150000
#define CIN   32
#define COUT  64
#define EPSF  1e-5f
#define NCOPY 16

#define NTHR   256
#define NTILES (NV / 16)              // 9375 exact
#define NBLK1  ((NTILES + 3) / 4)     // 2344 blocks, 1 tile per wave

// k_norm: chunks of 8 channels (one uint4 of bf16)
#define CH8    (NV * COUT / 8)        // 1,200,000
#define NBLK2  1172
#define STRIDE2 (NBLK2 * NTHR)        // 300,032 (divisible by 8)

// ws layout (bytes):
//   [0, 110592)             ushort wfrag[27*4*64*8]  (B-fragment swizzled)
//   [110592, 118784)        float  gstats[NCOPY*128]
//   [118784, 19318784)      ushort out_bf[NV*COUT]   (conv result, bf16)
#define WS_WFRAG  0
#define WS_GSTATS 110592
#define WS_OUTBF  118784

typedef short  bf16x8 __attribute__((ext_vector_type(8)));
typedef float  f32x4  __attribute__((ext_vector_type(4)));

union u4bf { uint4 u; bf16x8 h; };

__device__ __forceinline__ unsigned pack_bf2(float a, float b) {
    union { float f; unsigned u; } ca, cb;
    ca.f = a; cb.f = b;
    const unsigned lo = (ca.u + 0x7FFFu + ((ca.u >> 16) & 1u)) >> 16;
    const unsigned hi = (cb.u + 0x7FFFu + ((cb.u >> 16) & 1u)) & 0xFFFF0000u;
    return lo | hi;
}

__device__ __forceinline__ unsigned short bf16r(float a) {
    union { float f; unsigned u; } c; c.f = a;
    return (unsigned short)((c.u + 0x7FFFu + ((c.u >> 16) & 1u)) >> 16);
}

__device__ __forceinline__ u4bf pack_row(float4 f0, float4 f1) {
    u4bf r;
    r.u.x = pack_bf2(f0.x, f0.y);
    r.u.y = pack_bf2(f0.z, f0.w);
    r.u.z = pack_bf2(f1.x, f1.y);
    r.u.w = pack_bf2(f1.z, f1.w);
    return r;
}

// ---------------------------------------------------------------------------
// K0: prep — weights->B-fragment-swizzled bf16 (27 blocks) + gstats zero (1).
// ---------------------------------------------------------------------------
__global__ __launch_bounds__(NTHR) void k_prep(
    const float* __restrict__ weight,
    char*        __restrict__ ws)
{
    const int b = blockIdx.x;
    if (b < 27) {
        const int k    = b;
        const int bb   = threadIdx.x >> 6;       // cout block 0..3
        const int lane = threadIdx.x & 63;
        const int quad = lane >> 4;
        const int lm   = lane & 15;
        // entry holds weight[k][quad*8+j][bb*16+lm], j=0..7
        const float* wsrc = weight + (long)k * CIN * COUT + (quad * 8) * COUT + bb * 16 + lm;
        float f[8];
#pragma unroll
        for (int j = 0; j < 8; ++j) f[j] = wsrc[j * COUT];
        uint4 o;
        o.x = pack_bf2(f[0], f[1]);
        o.y = pack_bf2(f[2], f[3]);
        o.z = pack_bf2(f[4], f[5]);
        o.w = pack_bf2(f[6], f[7]);
        ((uint4*)(ws + WS_WFRAG))[(k * 4 + bb) * 64 + lane] = o;
    } else {
        float* gs = (float*)(ws + WS_GSTATS);
#pragma unroll
        for (int i = 0; i < 8; ++i) gs[threadIdx.x + i * NTHR] = 0.f;
    }
}

// ---------------------------------------------------------------------------
// K1: one wave per 16-voxel tile (round-10 structure). Feature rows read
// directly from f32 feat and packed to bf16 inline (once per use); weights
// pre-swizzled bf16 from ws. Writes conv result bf16. Fused BN partials.
// ---------------------------------------------------------------------------
__global__ __launch_bounds__(NTHR) void k_conv(
    const float* __restrict__ feat,    // [NV, CIN] f32
    char*        __restrict__ ws,      // wfrag + gstats + out_bf
    const int*   __restrict__ nbr,     // [27, NV]
    float*       __restrict__ gstats)
{
    const uint4* wf = (const uint4*)(ws + WS_WFRAG);    // wfrag[(k*4+b)*64+lane]
    unsigned short* ob = (unsigned short*)(ws + WS_OUTBF);

    const int tid  = threadIdx.x;
    const int lane = tid & 63;
    const int quad = lane >> 4;
    const int lm   = lane & 15;
    const int wid  = blockIdx.x * 4 + (tid >> 6);   // == tile id

    f32x4 ssum = {0.f, 0.f, 0.f, 0.f};
    f32x4 qsum = {0.f, 0.f, 0.f, 0.f};
    f32x4 acc[4] = {{0.f,0.f,0.f,0.f},{0.f,0.f,0.f,0.f},{0.f,0.f,0.f,0.f},{0.f,0.f,0.f,0.f}};

    const bool have_tile = (wid < NTILES);
    const int v0 = have_tile ? wid * 16 : 0;

    if (have_tile) {
        // ---- 1) scan loads: 26 taps x 16 voxels = 416 items ----
        int sidx[7];
#pragma unroll
        for (int it = 0; it < 7; ++it) {
            const int item = lane + it * 64;
            int idx = -1;
            if (item < 416) {
                const int kp = item >> 4;
                const int k  = kp + (kp >= 13);
                idx = nbr[(long)k * NV + v0 + (item & 15)];
            }
            sidx[it] = idx;
        }

        // ---- 2) center tap MFMA (f32 feat row packed inline) ----
        {
            const float4* fp = (const float4*)(feat + (long)(v0 + lm) * CIN + quad * 8);
            const u4bf a0 = pack_row(fp[0], fp[1]);
#pragma unroll
            for (int b = 0; b < 4; ++b) {
                u4bf w; w.u = wf[(13 * 4 + b) * 64 + lane];
                acc[b] = __builtin_amdgcn_mfma_f32_16x16x32_bf16(a0.h, w.h, acc[b], 0, 0, 0);
            }
        }

        // ---- 3) ballots -> wave-uniform 26-bit active-k mask ----
        unsigned int kmask = 0u;
#pragma unroll
        for (int it = 0; it < 7; ++it) {
            const unsigned long long m = __ballot(sidx[it] >= 0);
            kmask |= ((m & 0xFFFFull)         ? 1u : 0u) << (it * 4 + 0);
            kmask |= (((m >> 16) & 0xFFFFull) ? 1u : 0u) << (it * 4 + 1);
            kmask |= (((m >> 32) & 0xFFFFull) ? 1u : 0u) << (it * 4 + 2);
            kmask |= ((m >> 48)               ? 1u : 0u) << (it * 4 + 3);
        }

        // ---- 4) drain: 2 active k's per iteration ----
        while (kmask) {
            const int kpA = __ffs(kmask) - 1;
            kmask &= kmask - 1u;
            int kpB = -1;
            if (kmask) { kpB = __ffs(kmask) - 1; kmask &= kmask - 1u; }
            const int kA = kpA + (kpA >= 13);
            const int kB = (kpB >= 0) ? (kpB + (kpB >= 13)) : kA;

            int rawA, rawB;
            switch (kpA >> 2) {
                case 0: rawA = sidx[0]; break; case 1: rawA = sidx[1]; break;
                case 2: rawA = sidx[2]; break; case 3: rawA = sidx[3]; break;
                case 4: rawA = sidx[4]; break; case 5: rawA = sidx[5]; break;
                default: rawA = sidx[6]; break;
            }
            const int kpB2 = (kpB >= 0) ? kpB : kpA;
            switch (kpB2 >> 2) {
                case 0: rawB = sidx[0]; break; case 1: rawB = sidx[1]; break;
                case 2: rawB = sidx[2]; break; case 3: rawB = sidx[3]; break;
                case 4: rawB = sidx[4]; break; case 5: rawB = sidx[5]; break;
                default: rawB = sidx[6]; break;
            }
            const int idxA = __shfl(rawA, ((kpA & 3) << 4) | lm);
            int idxB = __shfl(rawB, ((kpB2 & 3) << 4) | lm);
            if (kpB < 0) idxB = -1;

            const float4* fpA = (const float4*)(feat + (long)(idxA < 0 ? 0 : idxA) * CIN + quad * 8);
            const float4* fpB = (const float4*)(feat + (long)(idxB < 0 ? 0 : idxB) * CIN + quad * 8);
            u4bf aA = pack_row(fpA[0], fpA[1]);
            u4bf aB = pack_row(fpB[0], fpB[1]);
            if (idxA < 0) aA.u = make_uint4(0u, 0u, 0u, 0u);
            if (idxB < 0) aB.u = make_uint4(0u, 0u, 0u, 0u);

#pragma unroll
            for (int b = 0; b < 4; ++b) {
                u4bf wA, wB;
                wA.u = wf[(kA * 4 + b) * 64 + lane];
                wB.u = wf[(kB * 4 + b) * 64 + lane];
                acc[b] = __builtin_amdgcn_mfma_f32_16x16x32_bf16(aA.h, wA.h, acc[b], 0, 0, 0);
                acc[b] = __builtin_amdgcn_mfma_f32_16x16x32_bf16(aB.h, wB.h, acc[b], 0, 0, 0);
            }
        }

        // ---- 5) store bf16 rows + BN partials from f32 values ----
#pragma unroll
        for (int b = 0; b < 4; ++b) {
            const float r0 = acc[b][0], r1 = acc[b][1], r2 = acc[b][2], r3 = acc[b][3];
            ob[(long)(v0 + quad * 4 + 0) * COUT + b * 16 + lm] = bf16r(r0);
            ob[(long)(v0 + quad * 4 + 1) * COUT + b * 16 + lm] = bf16r(r1);
            ob[(long)(v0 + quad * 4 + 2) * COUT + b * 16 + lm] = bf16r(r2);
            ob[(long)(v0 + quad * 4 + 3) * COUT + b * 16 + lm] = bf16r(r3);
            ssum[b] += r0 + r1 + r2 + r3;
            qsum[b] += r0 * r0 + r1 * r1 + r2 * r2 + r3 * r3;
        }
    }

    // ---- butterfly over quads ----
#pragma unroll
    for (int off = 16; off < 64; off <<= 1) {
#pragma unroll
        for (int b = 0; b < 4; ++b) {
            ssum[b] += __shfl_xor(ssum[b], off);
            qsum[b] += __shfl_xor(qsum[b], off);
        }
    }

    __shared__ float ls[4][128];
    const int wv = tid >> 6;
    if (quad == 0) {
#pragma unroll
        for (int b = 0; b < 4; ++b) {
            ls[wv][b * 16 + lm]      = ssum[b];
            ls[wv][64 + b * 16 + lm] = qsum[b];
        }
    }
    __syncthreads();
    if (tid < 128) {
        const float v = ls[0][tid] + ls[1][tid] + ls[2][tid] + ls[3][tid];
        atomicAdd(gstats + (blockIdx.x & (NCOPY - 1)) * 128 + tid, v);
    }
}

// ---------------------------------------------------------------------------
// K2: stripe reduce -> scale/shift, then read bf16 conv result, apply
// affine + ReLU, write f32 d_out.
// ---------------------------------------------------------------------------
__global__ __launch_bounds__(NTHR) void k_norm(
    const char*  __restrict__ ws_ro,   // out_bf
    float*       __restrict__ out,
    const float* __restrict__ gstats,
    const float* __restrict__ gamma,
    const float* __restrict__ beta)
{
    __shared__ float sscale[COUT];
    __shared__ float sshift[COUT];
    const int tid = threadIdx.x;
    if (tid < COUT) {
        float s = 0.f, q = 0.f;
#pragma unroll
        for (int cp = 0; cp < NCOPY; ++cp) {
            s += gstats[cp * 128 + tid];
            q += gstats[cp * 128 + 64 + tid];
        }
        const float inv_n = 1.f / (float)NV;
        const float mean = s * inv_n;
        float var = q * inv_n - mean * mean;
        var = fmaxf(var, 0.f);
        const float rstd = rsqrtf(var + EPSF);
        const float sc = gamma[tid] * rstd;
        sscale[tid] = sc;
        sshift[tid] = beta[tid] - mean * sc;
    }
    __syncthreads();

    const int  base = blockIdx.x * NTHR + tid;     // chunk id (8 channels)
    const int  g8   = (base & 7) * 8;              // fixed: STRIDE2 % 8 == 0
    const float4 SC0 = make_float4(sscale[g8],   sscale[g8+1], sscale[g8+2], sscale[g8+3]);
    const float4 SC1 = make_float4(sscale[g8+4], sscale[g8+5], sscale[g8+6], sscale[g8+7]);
    const float4 SH0 = make_float4(sshift[g8],   sshift[g8+1], sshift[g8+2], sshift[g8+3]);
    const float4 SH1 = make_float4(sshift[g8+4], sshift[g8+5], sshift[g8+6], sshift[g8+7]);

    const uint4* ib = (const uint4*)(ws_ro + WS_OUTBF);
    float4* o4 = (float4*)out;

#pragma unroll
    for (int n = 0; n < 4; ++n) {
        const int c = base + n * STRIDE2;
        if (n == 3 && c >= CH8) break;
        const uint4 u = ib[c];
        union { unsigned u; float f; } t;
        float4 v0, v1;
        t.u = u.x << 16;          v0.x = t.f;
        t.u = u.x & 0xFFFF0000u;  v0.y = t.f;
        t.u = u.y << 16;          v0.z = t.f;
        t.u = u.y & 0xFFFF0000u;  v0.w = t.f;
        t.u = u.z << 16;          v1.x = t.f;
        t.u = u.z & 0xFFFF0000u;  v1.y = t.f;
        t.u = u.w << 16;          v1.z = t.f;
        t.u = u.w & 0xFFFF0000u;  v1.w = t.f;

        v0.x = fmaxf(v0.x * SC0.x + SH0.x, 0.f);
        v0.y = fmaxf(v0.y * SC0.y + SH0.y, 0.f);
        v0.z = fmaxf(v0.z * SC0.z + SH0.z, 0.f);
        v0.w = fmaxf(v0.w * SC0.w + SH0.w, 0.f);
        v1.x = fmaxf(v1.x * SC1.x + SH1.x, 0.f);
        v1.y = fmaxf(v1.y * SC1.y + SH1.y, 0.f);
        v1.z = fmaxf(v1.z * SC1.z + SH1.z, 0.f);
        v1.w = fmaxf(v1.w * SC1.w + SH1.w, 0.f);

        o4[(long)c * 2]     = v0;
        o4[(long)c * 2 + 1] = v1;
    }
}

// ---------------------------------------------------------------------------
extern "C" void kernel_launch(void* const* d_in, const int* in_sizes, int n_in,
                              void* d_out, int out_size, void* d_ws, size_t ws_size,
                              hipStream_t stream) {
    const float* feat   = (const float*)d_in[0];
    const float* weight = (const float*)d_in[1];
    const float* gamma  = (const float*)d_in[2];
    const float* beta   = (const float*)d_in[3];
    const int*   nbr    = (const int*)d_in[4];
    float* out = (float*)d_out;

    char*  ws     = (char*)d_ws;
    float* gstats = (float*)(ws + WS_GSTATS);

    k_prep<<<28, NTHR, 0, stream>>>(weight, ws);
    k_conv<<<NBLK1, NTHR, 0, stream>>>(feat, ws, nbr, gstats);
    k_norm<<<NBLK2, NTHR, 0, stream>>>(ws, out, gstats, gamma, beta);
}